// Round 6
// baseline (236.616 us; speedup 1.0000x reference)
//
#include <hip/hip_runtime.h>

typedef __bf16 bf16_t;
typedef __attribute__((ext_vector_type(8))) __bf16 bf16x8;
typedef __attribute__((ext_vector_type(4))) __bf16 bf16x4;
typedef __attribute__((ext_vector_type(2))) __bf16 bf16x2;
typedef __attribute__((ext_vector_type(4))) float floatx4;
typedef __attribute__((ext_vector_type(4))) unsigned uintx4;

#define LOG2E 1.4426950408889634f

// async global->LDS, 16B per lane. LDS dest is wave-uniform base; HW adds lane*16.
__device__ __forceinline__ void async16(const void* g, void* l) {
  __builtin_amdgcn_global_load_lds(
      (const __attribute__((address_space(1))) void*)g,
      (__attribute__((address_space(3))) void*)l, 16, 0, 0);
}

// ---------------- fused cast f32 -> bf16 (x, wq, wk, wv, wo -> contiguous ws) --------
__global__ __launch_bounds__(256) void cast_all(
    const float* __restrict__ x, const float* __restrict__ wq,
    const float* __restrict__ wk, const float* __restrict__ wv,
    const float* __restrict__ wo, bf16_t* __restrict__ dst) {
  int i = (blockIdx.x * 256 + threadIdx.x) * 4;
  const float* src;
  int off;
  if (i < 4194304) {
    src = x; off = i;
  } else {
    int j = i - 4194304;
    int w = j >> 20;
    off = j & 1048575;
    src = (w == 0) ? wq : (w == 1) ? wk : (w == 2) ? wv : wo;
  }
  float4 v = *(const float4*)(src + off);
  bf16x4 o;
  o[0] = (bf16_t)v.x; o[1] = (bf16_t)v.y; o[2] = (bf16_t)v.z; o[3] = (bf16_t)v.w;
  *(bf16x4*)(dst + i) = o;
}

// ---- 128x128 GEMM core, BK=32, DOUBLE-BUFFERED, swizzled: C = A x W^T (K=1024) ----
// LDS per buf: A 8KB + B 8KB; 2 bufs = 32KB. Swizzle: stored chunk = c ^ ((row>>1)&3)
// -> read cq = quad ^ ((l15>>1)&3); lanes 0..7 cover all 8 bank groups (conflict-free).
__device__ __forceinline__ void gemm128(const bf16_t* __restrict__ A,
                                        const bf16_t* __restrict__ W,
                                        int tileM, int tileN, char* smem,
                                        floatx4 acc[4][4]) {
  const int tid = threadIdx.x;
  const int lane = tid & 63;
  const int quad = lane >> 4;
  const int l15 = lane & 15;
  const int wid = tid >> 6;
  const int waveM = (wid >> 1) << 6;
  const int waveN = (wid & 1) << 6;
  const int swz = (l15 >> 1) & 3;
  for (int i = 0; i < 4; ++i)
    for (int j = 0; j < 4; ++j)
      for (int r = 0; r < 4; ++r) acc[i][j][r] = 0.0f;

  // staging: thread covers (row tid>>2 [+64], stored chunk tid&3); source col swizzled
  const int r0 = tid >> 2;
  const int sc = ((tid & 3) ^ ((r0 >> 1) & 3)) << 3;
  const size_t abase = (size_t)(tileM + r0) * 1024 + sc;
  const size_t bbase = (size_t)(tileN + r0) * 1024 + sc;
  const int ldbase = (tid & ~63) * 16;   // wave-uniform; HW adds lane*16 -> tid*16

  // prefetch kt=0 -> buf 0
  async16(A + abase, smem + ldbase);
  async16(A + abase + (size_t)64 * 1024, smem + 4096 + ldbase);
  async16(W + bbase, smem + 8192 + ldbase);
  async16(W + bbase + (size_t)64 * 1024, smem + 12288 + ldbase);
  __syncthreads();

  for (int kt = 0; kt < 32; ++kt) {
    const int cur = kt & 1;
    char* cb = smem + cur * 16384;
    if (kt < 31) {   // prefetch kt+1 into other buffer; has full compute phase in flight
      char* nb = smem + (cur ^ 1) * 16384;
      const size_t ko = (size_t)(kt + 1) * 32;
      async16(A + abase + ko, nb + ldbase);
      async16(A + abase + (size_t)64 * 1024 + ko, nb + 4096 + ldbase);
      async16(W + bbase + ko, nb + 8192 + ldbase);
      async16(W + bbase + (size_t)64 * 1024 + ko, nb + 12288 + ldbase);
    }
    bf16_t* As = (bf16_t*)cb;
    bf16_t* Bs = (bf16_t*)(cb + 8192);
    const int cq = (quad ^ swz) << 3;
    bf16x8 af[4], bfr[4];
    for (int rb = 0; rb < 4; ++rb)
      af[rb] = *(const bf16x8*)&As[(waveM + rb * 16 + l15) * 32 + cq];
    for (int cbi = 0; cbi < 4; ++cbi)
      bfr[cbi] = *(const bf16x8*)&Bs[(waveN + cbi * 16 + l15) * 32 + cq];
    for (int rb = 0; rb < 4; ++rb)
      for (int cbi = 0; cbi < 4; ++cbi)
        acc[rb][cbi] = __builtin_amdgcn_mfma_f32_16x16x32_bf16(af[rb], bfr[cbi],
                                                               acc[rb][cbi], 0, 0, 0);
    __syncthreads();
  }
}

// ---- 64x128 GEMM core, BK=32, double-buffered, swizzled (proj_o) ----
// LDS per buf: A 4KB + B 8KB; 2 bufs = 24KB.
__device__ __forceinline__ void gemm64x128(const bf16_t* __restrict__ A,
                                           const bf16_t* __restrict__ W,
                                           int tileM, int tileN, char* smem,
                                           floatx4 acc[2][4]) {
  const int tid = threadIdx.x;
  const int lane = tid & 63;
  const int quad = lane >> 4;
  const int l15 = lane & 15;
  const int wid = tid >> 6;
  const int waveM = (wid >> 1) * 32;
  const int waveN = (wid & 1) * 64;
  const int swz = (l15 >> 1) & 3;
  for (int i = 0; i < 2; ++i)
    for (int j = 0; j < 4; ++j)
      for (int r = 0; r < 4; ++r) acc[i][j][r] = 0.0f;

  const int r0 = tid >> 2;
  const int sc = ((tid & 3) ^ ((r0 >> 1) & 3)) << 3;
  const size_t abase = (size_t)(tileM + r0) * 1024 + sc;
  const size_t bbase = (size_t)(tileN + r0) * 1024 + sc;
  const int ldbase = (tid & ~63) * 16;

  // prefetch kt=0 -> buf 0 (buf b at smem + b*12288: A [0,4K), B [4K,12K))
  async16(A + abase, smem + ldbase);
  async16(W + bbase, smem + 4096 + ldbase);
  async16(W + bbase + (size_t)64 * 1024, smem + 8192 + ldbase);
  __syncthreads();

  for (int kt = 0; kt < 32; ++kt) {
    const int cur = kt & 1;
    char* cb = smem + cur * 12288;
    if (kt < 31) {
      char* nb = smem + (cur ^ 1) * 12288;
      const size_t ko = (size_t)(kt + 1) * 32;
      async16(A + abase + ko, nb + ldbase);
      async16(W + bbase + ko, nb + 4096 + ldbase);
      async16(W + bbase + (size_t)64 * 1024 + ko, nb + 8192 + ldbase);
    }
    bf16_t* As = (bf16_t*)cb;
    bf16_t* Bs = (bf16_t*)(cb + 4096);
    const int cq = (quad ^ swz) << 3;
    bf16x8 af[2], bfr[4];
    for (int rb = 0; rb < 2; ++rb)
      af[rb] = *(const bf16x8*)&As[(waveM + rb * 16 + l15) * 32 + cq];
    for (int cbi = 0; cbi < 4; ++cbi)
      bfr[cbi] = *(const bf16x8*)&Bs[(waveN + cbi * 16 + l15) * 32 + cq];
    for (int rb = 0; rb < 2; ++rb)
      for (int cbi = 0; cbi < 4; ++cbi)
        acc[rb][cbi] = __builtin_amdgcn_mfma_f32_16x16x32_bf16(af[rb], bfr[cbi],
                                                               acc[rb][cbi], 0, 0, 0);
    __syncthreads();
  }
}

// ---------------- QKV projection (z selects Q/K/V) ----------------
__global__ __launch_bounds__(256) void proj_qkv(
    const bf16_t* __restrict__ xb, const bf16_t* __restrict__ wq,
    const bf16_t* __restrict__ wk, const bf16_t* __restrict__ wv,
    const float* __restrict__ cbias, const float* __restrict__ cv,
    bf16_t* __restrict__ qb, bf16_t* __restrict__ kb, bf16_t* __restrict__ vtb) {
  __shared__ __align__(16) char smem[128 * 136 * 2];   // 34816 (gemm staging uses 32 KB)
  const int mode = blockIdx.z;
  const bf16_t* W = (mode == 0) ? wq : ((mode == 1) ? wk : wv);
  const int tileM = blockIdx.y * 128, tileN = blockIdx.x * 128;
  floatx4 acc[4][4];
  gemm128(xb, W, tileM, tileN, smem, acc);
  const int tid = threadIdx.x, lane = tid & 63, quad = lane >> 4, l15 = lane & 15,
            wid = tid >> 6;
  const int waveM = (wid >> 1) << 6, waveN = (wid & 1) << 6;
  bf16_t* T = (bf16_t*)smem;                            // stride 136
  __syncthreads();
  for (int rb = 0; rb < 4; ++rb)
    for (int cb = 0; cb < 4; ++cb)
      for (int r = 0; r < 4; ++r) {
        int rl = waveM + rb * 16 + quad * 4 + r;        // token (local)
        int cl = waveN + cb * 16 + l15;                 // channel (local)
        float v = acc[rb][cb][r];
        if (mode == 0)
          v += cbias[tileN + cl] * cv[(size_t)(tileM + rl) * 1024 + tileN + cl];
        if (mode == 2)
          T[cl * 136 + rl] = (bf16_t)v;                 // [channel][token]
        else
          T[rl * 136 + cl] = (bf16_t)v;                 // [token][channel]
      }
  __syncthreads();
  const int rowi = tid >> 1, half = tid & 1;
  const bf16_t* src = T + rowi * 136 + half * 64;
  if (mode == 2) {
    int n = tileN + rowi;
    int b = tileM >> 11;
    int t0 = (tileM & 2047) + half * 64;
    bf16_t* dst = vtb + ((size_t)b * 1024 + n) * 2048 + t0;
    for (int i = 0; i < 8; ++i) *(bf16x8*)(dst + i * 8) = *(const bf16x8*)(src + i * 8);
  } else {
    int tg = tileM + rowi;
    int b = tg >> 11, t = tg & 2047;
    int n0 = tileN + half * 64;
    int h = n0 >> 6;
    bf16_t* base = (mode == 0) ? qb : kb;
    bf16_t* dst = base + ((size_t)(b * 16 + h) * 2048 + t) * 64;
    for (int i = 0; i < 8; ++i) *(bf16x8*)(dst + i * 8) = *(const bf16x8*)(src + i * 8);
  }
}

// ---------------- flash attention, causal, swapped-operand (S^T / O^T) ----------------
// S^T = K.Q^T: one query per lane (col=l15) -> softmax rows in-register (2 shfls).
// P^T stays in-lane: PV key mapping chosen so B-operand = in-lane repack of pk,
// and V^T A-operand reads the same mapping as two ds_read_b64. O^T = V^T.P^T.
__global__ __launch_bounds__(256) void attn_fwd(
    const bf16_t* __restrict__ qb, const bf16_t* __restrict__ kb,
    const bf16_t* __restrict__ vtb, bf16_t* __restrict__ ob) {
  __shared__ __align__(16) bf16_t Qs[64 * 64];      // [t][d], chunk-swizzled
  __shared__ __align__(16) bf16_t Ks[2][64 * 64];   // [key][d], swizzled
  __shared__ __align__(16) bf16_t Vs[2][64 * 64];   // [d][key], swizzled
  const int bh = blockIdx.x;
  const int qt = 31 - blockIdx.y;                   // heavy blocks dispatch first
  const int q0 = qt * 64;
  const int tid = threadIdx.x, lane = tid & 63, w = tid >> 6, quad = lane >> 4,
            l15 = lane & 15;

  // staging map: thread tid covers chunks {tid, tid+256} of 512 (64 rows x 8 chunks)
  const int sr = tid >> 3;                 // row 0..31 (and +32)
  const int sc = (tid & 7) ^ (sr & 7);     // swizzled source chunk
  const int ldst = (tid & ~63) * 16;       // wave-uniform byte offset in tile
  const int swz = l15 & 7;                 // read-side swizzle key

  {
    const bf16_t* gq = qb + ((size_t)bh * 2048 + q0 + sr) * 64 + sc * 8;
    async16(gq, (char*)Qs + ldst);
    async16(gq + 32 * 64, (char*)Qs + ldst + 4096);
  }

  floatx4 O[4];   // O^T: [db], reg r -> d = db*16+quad*4+r, q = w*16+l15
  for (int d = 0; d < 4; ++d)
    for (int r = 0; r < 4; ++r) O[d][r] = 0.f;
  float m_c = -1e30f, l_c = 0.f;
  const float SC = 0.125f * LOG2E;   // 1/sqrt(64) folded into exp2 domain

  // prefetch tile 0 into buf 0
  {
    const bf16_t* gk = kb + ((size_t)bh * 2048 + sr) * 64 + sc * 8;
    async16(gk, (char*)Ks[0] + ldst);
    async16(gk + 32 * 64, (char*)Ks[0] + ldst + 4096);
    const bf16_t* gv = vtb + ((size_t)bh * 64 + sr) * 2048 + sc * 8;
    async16(gv, (char*)Vs[0] + ldst);
    async16(gv + (size_t)32 * 2048, (char*)Vs[0] + ldst + 4096);
  }
  __syncthreads();

  // loop-invariant Q fragments (B-operand: B[k=d][n=q], q = w*16+l15)
  bf16x8 qf[2];
  for (int ks = 0; ks < 2; ++ks) {
    const int cq = (ks * 4 + quad) ^ swz;
    qf[ks] = *(const bf16x8*)&Qs[(w * 16 + l15) * 64 + cq * 8];
  }

  for (int kt = 0; kt <= qt; ++kt) {
    const int cur = kt & 1;
    if (kt < qt) {           // prefetch kt+1 into other buffer (overlaps compute)
      const int nxt = cur ^ 1;
      const bf16_t* gk2 = kb + ((size_t)bh * 2048 + (kt + 1) * 64 + sr) * 64 + sc * 8;
      async16(gk2, (char*)Ks[nxt] + ldst);
      async16(gk2 + 32 * 64, (char*)Ks[nxt] + ldst + 4096);
      const bf16_t* gv2 = vtb + ((size_t)bh * 64 + sr) * 2048 + (size_t)(kt + 1) * 64 + sc * 8;
      async16(gv2, (char*)Vs[nxt] + ldst);
      async16(gv2 + (size_t)32 * 2048, (char*)Vs[nxt] + ldst + 4096);
    }
    // S^T = K x Q^T : s[kbt] covers keys kbt*16+quad*4+r, query w*16+l15
    floatx4 s[4];
    for (int i = 0; i < 4; ++i)
      for (int r = 0; r < 4; ++r) s[i][r] = 0.f;
    for (int ks = 0; ks < 2; ++ks) {
      const int cq = (ks * 4 + quad) ^ swz;
      for (int kbt = 0; kbt < 4; ++kbt) {
        bf16x8 kf = *(const bf16x8*)&Ks[cur][(kbt * 16 + l15) * 64 + cq * 8];
        s[kbt] = __builtin_amdgcn_mfma_f32_16x16x32_bf16(kf, qf[ks], s[kbt], 0, 0, 0);
      }
    }
    // causal mask only on the diagonal tile (wave-uniform branch)
    if (kt == qt) {
      const int qloc = w * 16 + l15;
      for (int kbt = 0; kbt < 4; ++kbt)
        for (int r = 0; r < 4; ++r)
          if (kbt * 16 + quad * 4 + r > qloc) s[kbt][r] = -1e30f;
    }
    // row-max: 15 in-lane fmax + 2 cross-quad shfls
    float mx = s[0][0];
    for (int i = 0; i < 4; ++i)
      for (int r = 0; r < 4; ++r) mx = fmaxf(mx, s[i][r]);
    mx = fmaxf(mx, __shfl_xor(mx, 16));
    mx = fmaxf(mx, __shfl_xor(mx, 32));
    const float m_new = fmaxf(m_c, mx);
    const float alpha = exp2f((m_c - m_new) * SC);
    const float msc = m_new * SC;
    m_c = m_new;
    float p[4][4];
    float rs = 0.f;
    for (int i = 0; i < 4; ++i)
      for (int r = 0; r < 4; ++r) {
        float v = exp2f(fmaf(s[i][r], SC, -msc));
        p[i][r] = v;
        rs += v;
      }
    rs += __shfl_xor(rs, 16);
    rs += __shfl_xor(rs, 32);
    l_c = l_c * alpha + rs;
    for (int db = 0; db < 4; ++db)
      for (int r = 0; r < 4; ++r) O[db][r] *= alpha;
    // pack p into bf16 pairs: pk[i][rr] = keys i*16 + quad*4 + {2rr, 2rr+1}
    unsigned pk[4][2];
    for (int i = 0; i < 4; ++i)
      for (int rr = 0; rr < 2; ++rr) {
        bf16x2 t2;
        t2[0] = (bf16_t)p[i][2 * rr];
        t2[1] = (bf16_t)p[i][2 * rr + 1];
        pk[i][rr] = __builtin_bit_cast(unsigned, t2);
      }
    // PV key mapping (k = quad*8+j within MFMA chunk c):
    //   j in [0,4): key = (2c)*16   + quad*4 + j
    //   j in [4,8): key = (2c+1)*16 + quad*4 + (j-4)
    // -> B-operand = pure in-lane repack of pk; A-operand (V^T) = 2x ds_read_b64.
    for (int c = 0; c < 2; ++c) {
      uintx4 bw;
      bw[0] = pk[2 * c][0];
      bw[1] = pk[2 * c][1];
      bw[2] = pk[2 * c + 1][0];
      bw[3] = pk[2 * c + 1][1];
      bf16x8 pfrag = __builtin_bit_cast(bf16x8, bw);
      const int ch0 = (4 * c + (quad >> 1)) ^ swz;       // elems (2c)*16 + quad*4 ..
      const int ch1 = (4 * c + 2 + (quad >> 1)) ^ swz;   // elems (2c+1)*16 + quad*4 ..
      const int sub = (quad & 1) * 4;
      for (int db = 0; db < 4; ++db) {
        const bf16_t* vrow = &Vs[cur][(db * 16 + l15) * 64];
        bf16x4 lo = *(const bf16x4*)(vrow + ch0 * 8 + sub);
        bf16x4 hi = *(const bf16x4*)(vrow + ch1 * 8 + sub);
        bf16x8 vf;
        for (int e = 0; e < 4; ++e) { vf[e] = lo[e]; vf[e + 4] = hi[e]; }
        O[db] = __builtin_amdgcn_mfma_f32_16x16x32_bf16(vf, pfrag, O[db], 0, 0, 0);
      }
    }
    __syncthreads();  // drains prefetch vmcnt; all waves done reading cur
  }
  const int b = bh >> 4, h = bh & 15;
  const float inv = 1.0f / l_c;
  const int t = q0 + w * 16 + l15;
  for (int db = 0; db < 4; ++db) {
    bf16x4 o4;
    for (int r = 0; r < 4; ++r) o4[r] = (bf16_t)(O[db][r] * inv);
    *(bf16x4*)&ob[((size_t)b * 2048 + t) * 1024 + h * 64 + db * 16 + quad * 4] = o4;
  }
}

// ---------------- output projection: out = ob @ wo^T + bo (fp32 out) ----------------
__global__ __launch_bounds__(256) void proj_o(
    const bf16_t* __restrict__ ain, const bf16_t* __restrict__ wo,
    const float* __restrict__ bo, float* __restrict__ out) {
  __shared__ __align__(16) char smem[24576];
  const int tileM = blockIdx.y * 64, tileN = blockIdx.x * 128;
  floatx4 acc[2][4];
  gemm64x128(ain, wo, tileM, tileN, smem, acc);
  const int tid = threadIdx.x, lane = tid & 63, quad = lane >> 4, l15 = lane & 15,
            wid = tid >> 6;
  const int waveM = (wid >> 1) * 32, waveN = (wid & 1) * 64;
  for (int rb = 0; rb < 2; ++rb)
    for (int cb = 0; cb < 4; ++cb)
      for (int r = 0; r < 4; ++r) {
        int row = tileM + waveM + rb * 16 + quad * 4 + r;
        int col = tileN + waveN + cb * 16 + l15;
        out[(size_t)row * 1024 + col] = acc[rb][cb][r] + bo[col];
      }
}

extern "C" void kernel_launch(void* const* d_in, const int* in_sizes, int n_in,
                              void* d_out, int out_size, void* d_ws, size_t ws_size,
                              hipStream_t stream) {
  const float* x     = (const float*)d_in[0];
  // d_in[1] = mask: tril causal by construction -> handled analytically
  const float* cv    = (const float*)d_in[2];
  const float* wq    = (const float*)d_in[3];
  const float* wk    = (const float*)d_in[4];
  const float* wv    = (const float*)d_in[5];
  const float* wo    = (const float*)d_in[6];
  const float* bo    = (const float*)d_in[7];
  const float* cbias = (const float*)d_in[8];
  float* out = (float*)d_out;

  char* ws = (char*)d_ws;
  const size_t MB = 1 << 20;
  bf16_t* xb  = (bf16_t*)(ws + 0 * MB);    // [4096,1024]
  bf16_t* wqb = (bf16_t*)(ws + 8 * MB);    // [1024,1024]
  bf16_t* wkb = (bf16_t*)(ws + 10 * MB);
  bf16_t* wvb = (bf16_t*)(ws + 12 * MB);
  bf16_t* wob = (bf16_t*)(ws + 14 * MB);
  bf16_t* qb  = (bf16_t*)(ws + 16 * MB);   // [32][2048][64]
  bf16_t* kb  = (bf16_t*)(ws + 24 * MB);   // [32][2048][64]
  bf16_t* vtb = (bf16_t*)(ws + 32 * MB);   // [32][64][2048] (transposed)
  bf16_t* ob  = (bf16_t*)(ws + 40 * MB);   // [4096,1024]

  cast_all<<<8192, 256, 0, stream>>>(x, wq, wk, wv, wo, xb);
  proj_qkv<<<dim3(8, 32, 3), 256, 0, stream>>>(xb, wqb, wkb, wvb, cbias, cv, qb, kb, vtb);
  attn_fwd<<<dim3(32, 32), 256, 0, stream>>>(qb, kb, vtb, ob);
  proj_o<<<dim3(8, 64), 256, 0, stream>>>(ob, wob, bo, out);
}

// Round 7
// 216.005 us; speedup vs baseline: 1.0954x; 1.0954x over previous
//
#include <hip/hip_runtime.h>

typedef __bf16 bf16_t;
typedef __attribute__((ext_vector_type(8))) __bf16 bf16x8;
typedef __attribute__((ext_vector_type(4))) __bf16 bf16x4;
typedef __attribute__((ext_vector_type(2))) __bf16 bf16x2;
typedef __attribute__((ext_vector_type(4))) float floatx4;
typedef __attribute__((ext_vector_type(4))) unsigned uintx4;

#define LOG2E 1.4426950408889634f

// async global->LDS, 16B per lane. LDS dest is wave-uniform base; HW adds lane*16.
__device__ __forceinline__ void async16(const void* g, void* l) {
  __builtin_amdgcn_global_load_lds(
      (const __attribute__((address_space(1))) void*)g,
      (__attribute__((address_space(3))) void*)l, 16, 0, 0);
}

// ---------------- fused cast f32 -> bf16 (x, wq, wk, wv, wo -> contiguous ws) --------
__global__ __launch_bounds__(256) void cast_all(
    const float* __restrict__ x, const float* __restrict__ wq,
    const float* __restrict__ wk, const float* __restrict__ wv,
    const float* __restrict__ wo, bf16_t* __restrict__ dst) {
  int i = (blockIdx.x * 256 + threadIdx.x) * 4;
  const float* src;
  int off;
  if (i < 4194304) {
    src = x; off = i;
  } else {
    int j = i - 4194304;
    int w = j >> 20;
    off = j & 1048575;
    src = (w == 0) ? wq : (w == 1) ? wk : (w == 2) ? wv : wo;
  }
  float4 v = *(const float4*)(src + off);
  bf16x4 o;
  o[0] = (bf16_t)v.x; o[1] = (bf16_t)v.y; o[2] = (bf16_t)v.z; o[3] = (bf16_t)v.w;
  *(bf16x4*)(dst + i) = o;
}

// ------- 64x128 GEMM core, BK=64, 2-barrier, XOR-swizzled (round-5 validated) --------
// LDS: A [64][64] 8KB + B [128][64] 16KB = 24KB. 16 K-iterations.
__device__ __forceinline__ void gemm64x128(const bf16_t* __restrict__ A,
                                           const bf16_t* __restrict__ W,
                                           int tileM, int tileN, char* smem,
                                           floatx4 acc[2][4]) {
  bf16_t* As = (bf16_t*)smem;              // [64][64], chunk-swizzled
  bf16_t* Bs = (bf16_t*)(smem + 8192);     // [128][64], chunk-swizzled
  const int tid = threadIdx.x;
  const int lane = tid & 63;
  const int quad = lane >> 4;
  const int l15 = lane & 15;
  const int wid = tid >> 6;
  const int waveM = (wid >> 1) * 32;
  const int waveN = (wid & 1) * 64;
  const int swz = l15 & 7;
  for (int i = 0; i < 2; ++i)
    for (int j = 0; j < 4; ++j)
      for (int r = 0; r < 4; ++r) acc[i][j][r] = 0.0f;

  const int r0 = tid >> 3;
  const int sc = ((tid & 7) ^ (r0 & 7)) << 3;
  const size_t abase = (size_t)(tileM + r0) * 1024 + sc;
  const size_t bbase = (size_t)(tileN + r0) * 1024 + sc;
  const int ldbase = (tid & ~63) * 16;

  for (int kt = 0; kt < 1024; kt += 64) {
    if (kt) __syncthreads();
    for (int j = 0; j < 2; ++j)
      async16(A + abase + (size_t)j * 32 * 1024 + kt, smem + j * 4096 + ldbase);
    for (int j = 0; j < 4; ++j)
      async16(W + bbase + (size_t)j * 32 * 1024 + kt, smem + 8192 + j * 4096 + ldbase);
    __syncthreads();
    for (int kk = 0; kk < 2; ++kk) {
      const int cq = (((kk << 2) + quad) ^ swz) << 3;
      bf16x8 af[2], bfr[4];
      for (int rb = 0; rb < 2; ++rb)
        af[rb] = *(const bf16x8*)&As[(waveM + rb * 16 + l15) * 64 + cq];
      for (int cb = 0; cb < 4; ++cb)
        bfr[cb] = *(const bf16x8*)&Bs[(waveN + cb * 16 + l15) * 64 + cq];
      for (int rb = 0; rb < 2; ++rb)
        for (int cb = 0; cb < 4; ++cb)
          acc[rb][cb] = __builtin_amdgcn_mfma_f32_16x16x32_bf16(af[rb], bfr[cb],
                                                                acc[rb][cb], 0, 0, 0);
    }
  }
}

// ---------------- QKV projection, 64x128 tiles (grid 8 x 64 x 3 = 1536 blocks) -------
// Small tile -> 6 blocks/CU co-resident: barrier drains covered by TLP.
__global__ __launch_bounds__(256) void proj_qkv(
    const bf16_t* __restrict__ xb, const bf16_t* __restrict__ wq,
    const bf16_t* __restrict__ wk, const bf16_t* __restrict__ wv,
    const float* __restrict__ cbias, const float* __restrict__ cv,
    bf16_t* __restrict__ qb, bf16_t* __restrict__ kb, bf16_t* __restrict__ vtb) {
  __shared__ __align__(16) char smem[24576];   // gemm staging 24KB; epilogue <= 18.4KB
  const int mode = blockIdx.z;
  const bf16_t* W = (mode == 0) ? wq : ((mode == 1) ? wk : wv);
  const int tileM = blockIdx.y * 64, tileN = blockIdx.x * 128;
  floatx4 acc[2][4];
  gemm64x128(xb, W, tileM, tileN, smem, acc);
  const int tid = threadIdx.x, lane = tid & 63, quad = lane >> 4, l15 = lane & 15,
            wid = tid >> 6;
  const int waveM = (wid >> 1) * 32, waveN = (wid & 1) * 64;
  bf16_t* T = (bf16_t*)smem;
  __syncthreads();                                      // gemm LDS reads done
  for (int rb = 0; rb < 2; ++rb)
    for (int cb = 0; cb < 4; ++cb)
      for (int r = 0; r < 4; ++r) {
        int rl = waveM + rb * 16 + quad * 4 + r;        // token (local, 0..63)
        int cl = waveN + cb * 16 + l15;                 // channel (local, 0..127)
        float v = acc[rb][cb][r];
        if (mode == 0)
          v += cbias[tileN + cl] * cv[(size_t)(tileM + rl) * 1024 + tileN + cl];
        if (mode == 2)
          T[cl * 72 + rl] = (bf16_t)v;                  // [channel 128][token 64+pad]
        else
          T[rl * 136 + cl] = (bf16_t)v;                 // [token 64][channel 128+pad]
      }
  __syncthreads();
  if (mode == 2) {
    // V^T: 128 channels x 64 tokens; 2 threads/row, 32 tokens each
    const int rowi = tid >> 1, half = tid & 1;
    const bf16_t* src = T + rowi * 72 + half * 32;
    int n = tileN + rowi;                               // global channel = h*64+d
    int b = tileM >> 11;
    int t0 = (tileM & 2047) + half * 32;
    bf16_t* dst = vtb + ((size_t)b * 1024 + n) * 2048 + t0;
    for (int i = 0; i < 4; ++i) *(bf16x8*)(dst + i * 8) = *(const bf16x8*)(src + i * 8);
  } else {
    // Q/K: 64 tokens x 128 channels; 4 threads/row, 32 channels each
    const int rowi = tid >> 2, qtr = tid & 3;
    const bf16_t* src = T + rowi * 136 + qtr * 32;
    int tg = tileM + rowi;
    int b = tg >> 11, t = tg & 2047;
    int n0 = tileN + qtr * 32;
    int h = n0 >> 6;
    bf16_t* base = (mode == 0) ? qb : kb;
    bf16_t* dst = base + ((size_t)(b * 16 + h) * 2048 + t) * 64 + (n0 & 63);
    for (int i = 0; i < 4; ++i) *(bf16x8*)(dst + i * 8) = *(const bf16x8*)(src + i * 8);
  }
}

// ---------------- flash attention, causal, swapped-operand (S^T / O^T) ----------------
// S^T = K.Q^T: one query per lane (col=l15) -> softmax rows in-register (2 shfls).
// P^T stays in-lane: PV key mapping chosen so B-operand = in-lane repack of pk,
// and V^T A-operand reads the same mapping as two ds_read_b64. O^T = V^T.P^T.
__global__ __launch_bounds__(256) void attn_fwd(
    const bf16_t* __restrict__ qb, const bf16_t* __restrict__ kb,
    const bf16_t* __restrict__ vtb, bf16_t* __restrict__ ob) {
  __shared__ __align__(16) bf16_t Qs[64 * 64];      // [t][d], chunk-swizzled
  __shared__ __align__(16) bf16_t Ks[2][64 * 64];   // [key][d], swizzled
  __shared__ __align__(16) bf16_t Vs[2][64 * 64];   // [d][key], swizzled
  const int bh = blockIdx.x;
  const int qt = 31 - blockIdx.y;                   // heavy blocks dispatch first
  const int q0 = qt * 64;
  const int tid = threadIdx.x, lane = tid & 63, w = tid >> 6, quad = lane >> 4,
            l15 = lane & 15;

  const int sr = tid >> 3;                 // row 0..31 (and +32)
  const int sc = (tid & 7) ^ (sr & 7);     // swizzled source chunk
  const int ldst = (tid & ~63) * 16;       // wave-uniform byte offset in tile
  const int swz = l15 & 7;                 // read-side swizzle key

  {
    const bf16_t* gq = qb + ((size_t)bh * 2048 + q0 + sr) * 64 + sc * 8;
    async16(gq, (char*)Qs + ldst);
    async16(gq + 32 * 64, (char*)Qs + ldst + 4096);
  }

  floatx4 O[4];   // O^T: [db], reg r -> d = db*16+quad*4+r, q = w*16+l15
  for (int d = 0; d < 4; ++d)
    for (int r = 0; r < 4; ++r) O[d][r] = 0.f;
  float m_c = -1e30f, l_c = 0.f;
  const float SC = 0.125f * LOG2E;   // 1/sqrt(64) folded into exp2 domain

  // prefetch tile 0 into buf 0
  {
    const bf16_t* gk = kb + ((size_t)bh * 2048 + sr) * 64 + sc * 8;
    async16(gk, (char*)Ks[0] + ldst);
    async16(gk + 32 * 64, (char*)Ks[0] + ldst + 4096);
    const bf16_t* gv = vtb + ((size_t)bh * 64 + sr) * 2048 + sc * 8;
    async16(gv, (char*)Vs[0] + ldst);
    async16(gv + (size_t)32 * 2048, (char*)Vs[0] + ldst + 4096);
  }
  __syncthreads();

  // loop-invariant Q fragments (B-operand: B[k=d][n=q], q = w*16+l15)
  bf16x8 qf[2];
  for (int ks = 0; ks < 2; ++ks) {
    const int cq = (ks * 4 + quad) ^ swz;
    qf[ks] = *(const bf16x8*)&Qs[(w * 16 + l15) * 64 + cq * 8];
  }

  for (int kt = 0; kt <= qt; ++kt) {
    const int cur = kt & 1;
    if (kt < qt) {           // prefetch kt+1 into other buffer (overlaps compute)
      const int nxt = cur ^ 1;
      const bf16_t* gk2 = kb + ((size_t)bh * 2048 + (kt + 1) * 64 + sr) * 64 + sc * 8;
      async16(gk2, (char*)Ks[nxt] + ldst);
      async16(gk2 + 32 * 64, (char*)Ks[nxt] + ldst + 4096);
      const bf16_t* gv2 = vtb + ((size_t)bh * 64 + sr) * 2048 + (size_t)(kt + 1) * 64 + sc * 8;
      async16(gv2, (char*)Vs[nxt] + ldst);
      async16(gv2 + (size_t)32 * 2048, (char*)Vs[nxt] + ldst + 4096);
    }
    // S^T = K x Q^T : s[kbt] covers keys kbt*16+quad*4+r, query w*16+l15
    floatx4 s[4];
    for (int i = 0; i < 4; ++i)
      for (int r = 0; r < 4; ++r) s[i][r] = 0.f;
    for (int ks = 0; ks < 2; ++ks) {
      const int cq = (ks * 4 + quad) ^ swz;
      for (int kbt = 0; kbt < 4; ++kbt) {
        bf16x8 kf = *(const bf16x8*)&Ks[cur][(kbt * 16 + l15) * 64 + cq * 8];
        s[kbt] = __builtin_amdgcn_mfma_f32_16x16x32_bf16(kf, qf[ks], s[kbt], 0, 0, 0);
      }
    }
    // causal mask only on the diagonal tile (wave-uniform branch)
    if (kt == qt) {
      const int qloc = w * 16 + l15;
      for (int kbt = 0; kbt < 4; ++kbt)
        for (int r = 0; r < 4; ++r)
          if (kbt * 16 + quad * 4 + r > qloc) s[kbt][r] = -1e30f;
    }
    // row-max: 15 in-lane fmax + 2 cross-quad shfls
    float mx = s[0][0];
    for (int i = 0; i < 4; ++i)
      for (int r = 0; r < 4; ++r) mx = fmaxf(mx, s[i][r]);
    mx = fmaxf(mx, __shfl_xor(mx, 16));
    mx = fmaxf(mx, __shfl_xor(mx, 32));
    const float m_new = fmaxf(m_c, mx);
    const float alpha = exp2f((m_c - m_new) * SC);
    const float msc = m_new * SC;
    m_c = m_new;
    float p[4][4];
    float rs = 0.f;
    for (int i = 0; i < 4; ++i)
      for (int r = 0; r < 4; ++r) {
        float v = exp2f(fmaf(s[i][r], SC, -msc));
        p[i][r] = v;
        rs += v;
      }
    rs += __shfl_xor(rs, 16);
    rs += __shfl_xor(rs, 32);
    l_c = l_c * alpha + rs;
    for (int db = 0; db < 4; ++db)
      for (int r = 0; r < 4; ++r) O[db][r] *= alpha;
    // pack p into bf16 pairs: pk[i][rr] = keys i*16 + quad*4 + {2rr, 2rr+1}
    unsigned pk[4][2];
    for (int i = 0; i < 4; ++i)
      for (int rr = 0; rr < 2; ++rr) {
        bf16x2 t2;
        t2[0] = (bf16_t)p[i][2 * rr];
        t2[1] = (bf16_t)p[i][2 * rr + 1];
        pk[i][rr] = __builtin_bit_cast(unsigned, t2);
      }
    // PV key mapping (k = quad*8+j within MFMA chunk c):
    //   j in [0,4): key = (2c)*16   + quad*4 + j
    //   j in [4,8): key = (2c+1)*16 + quad*4 + (j-4)
    // -> B-operand = pure in-lane repack of pk; A-operand (V^T) = 2x ds_read_b64.
    for (int c = 0; c < 2; ++c) {
      uintx4 bw;
      bw[0] = pk[2 * c][0];
      bw[1] = pk[2 * c][1];
      bw[2] = pk[2 * c + 1][0];
      bw[3] = pk[2 * c + 1][1];
      bf16x8 pfrag = __builtin_bit_cast(bf16x8, bw);
      const int ch0 = (4 * c + (quad >> 1)) ^ swz;       // elems (2c)*16 + quad*4 ..
      const int ch1 = (4 * c + 2 + (quad >> 1)) ^ swz;   // elems (2c+1)*16 + quad*4 ..
      const int sub = (quad & 1) * 4;
      for (int db = 0; db < 4; ++db) {
        const bf16_t* vrow = &Vs[cur][(db * 16 + l15) * 64];
        bf16x4 lo = *(const bf16x4*)(vrow + ch0 * 8 + sub);
        bf16x4 hi = *(const bf16x4*)(vrow + ch1 * 8 + sub);
        bf16x8 vf;
        for (int e = 0; e < 4; ++e) { vf[e] = lo[e]; vf[e + 4] = hi[e]; }
        O[db] = __builtin_amdgcn_mfma_f32_16x16x32_bf16(vf, pfrag, O[db], 0, 0, 0);
      }
    }
    __syncthreads();  // drains prefetch vmcnt; all waves done reading cur
  }
  const int b = bh >> 4, h = bh & 15;
  const float inv = 1.0f / l_c;
  const int t = q0 + w * 16 + l15;
  for (int db = 0; db < 4; ++db) {
    bf16x4 o4;
    for (int r = 0; r < 4; ++r) o4[r] = (bf16_t)(O[db][r] * inv);
    *(bf16x4*)&ob[((size_t)b * 2048 + t) * 1024 + h * 64 + db * 16 + quad * 4] = o4;
  }
}

// ---------------- output projection: out = ob @ wo^T + bo (fp32 out) ----------------
__global__ __launch_bounds__(256) void proj_o(
    const bf16_t* __restrict__ ain, const bf16_t* __restrict__ wo,
    const float* __restrict__ bo, float* __restrict__ out) {
  __shared__ __align__(16) char smem[24576];
  const int tileM = blockIdx.y * 64, tileN = blockIdx.x * 128;
  floatx4 acc[2][4];
  gemm64x128(ain, wo, tileM, tileN, smem, acc);
  const int tid = threadIdx.x, lane = tid & 63, quad = lane >> 4, l15 = lane & 15,
            wid = tid >> 6;
  const int waveM = (wid >> 1) * 32, waveN = (wid & 1) * 64;
  for (int rb = 0; rb < 2; ++rb)
    for (int cb = 0; cb < 4; ++cb)
      for (int r = 0; r < 4; ++r) {
        int row = tileM + waveM + rb * 16 + quad * 4 + r;
        int col = tileN + waveN + cb * 16 + l15;
        out[(size_t)row * 1024 + col] = acc[rb][cb][r] + bo[col];
      }
}

extern "C" void kernel_launch(void* const* d_in, const int* in_sizes, int n_in,
                              void* d_out, int out_size, void* d_ws, size_t ws_size,
                              hipStream_t stream) {
  const float* x     = (const float*)d_in[0];
  // d_in[1] = mask: tril causal by construction -> handled analytically
  const float* cv    = (const float*)d_in[2];
  const float* wq    = (const float*)d_in[3];
  const float* wk    = (const float*)d_in[4];
  const float* wv    = (const float*)d_in[5];
  const float* wo    = (const float*)d_in[6];
  const float* bo    = (const float*)d_in[7];
  const float* cbias = (const float*)d_in[8];
  float* out = (float*)d_out;

  char* ws = (char*)d_ws;
  const size_t MB = 1 << 20;
  bf16_t* xb  = (bf16_t*)(ws + 0 * MB);    // [4096,1024]
  bf16_t* wqb = (bf16_t*)(ws + 8 * MB);    // [1024,1024]
  bf16_t* wkb = (bf16_t*)(ws + 10 * MB);
  bf16_t* wvb = (bf16_t*)(ws + 12 * MB);
  bf16_t* wob = (bf16_t*)(ws + 14 * MB);
  bf16_t* qb  = (bf16_t*)(ws + 16 * MB);   // [32][2048][64]
  bf16_t* kb  = (bf16_t*)(ws + 24 * MB);   // [32][2048][64]
  bf16_t* vtb = (bf16_t*)(ws + 32 * MB);   // [32][64][2048] (transposed)
  bf16_t* ob  = (bf16_t*)(ws + 40 * MB);   // [4096,1024]

  cast_all<<<8192, 256, 0, stream>>>(x, wq, wk, wv, wo, xb);
  proj_qkv<<<dim3(8, 64, 3), 256, 0, stream>>>(xb, wqb, wkb, wvb, cbias, cv, qb, kb, vtb);
  attn_fwd<<<dim3(32, 32), 256, 0, stream>>>(qb, kb, vtb, ob);
  proj_o<<<dim3(8, 64), 256, 0, stream>>>(ob, wob, bo, out);
}

// Round 8
// 214.391 us; speedup vs baseline: 1.1037x; 1.0075x over previous
//
#include <hip/hip_runtime.h>

typedef __bf16 bf16_t;
typedef __attribute__((ext_vector_type(8))) __bf16 bf16x8;
typedef __attribute__((ext_vector_type(4))) __bf16 bf16x4;
typedef __attribute__((ext_vector_type(2))) __bf16 bf16x2;
typedef __attribute__((ext_vector_type(4))) float floatx4;
typedef __attribute__((ext_vector_type(4))) unsigned uintx4;

#define LOG2E 1.4426950408889634f

// async global->LDS, 16B per lane. LDS dest is wave-uniform base; HW adds lane*16.
__device__ __forceinline__ void async16(const void* g, void* l) {
  __builtin_amdgcn_global_load_lds(
      (const __attribute__((address_space(1))) void*)g,
      (__attribute__((address_space(3))) void*)l, 16, 0, 0);
}

// ---------------- fused cast f32 -> bf16 (x, wq, wk, wv, wo -> contiguous ws) --------
__global__ __launch_bounds__(256) void cast_all(
    const float* __restrict__ x, const float* __restrict__ wq,
    const float* __restrict__ wk, const float* __restrict__ wv,
    const float* __restrict__ wo, bf16_t* __restrict__ dst) {
  int i = (blockIdx.x * 256 + threadIdx.x) * 4;
  const float* src;
  int off;
  if (i < 4194304) {
    src = x; off = i;
  } else {
    int j = i - 4194304;
    int w = j >> 20;
    off = j & 1048575;
    src = (w == 0) ? wq : (w == 1) ? wk : (w == 2) ? wv : wo;
  }
  float4 v = *(const float4*)(src + off);
  bf16x4 o;
  o[0] = (bf16_t)v.x; o[1] = (bf16_t)v.y; o[2] = (bf16_t)v.z; o[3] = (bf16_t)v.w;
  *(bf16x4*)(dst + i) = o;
}

// ------- 64x128 GEMM core, BK=64, 2-barrier, XOR-swizzled (round-5 validated) --------
// LDS: A [64][64] 8KB + B [128][64] 16KB = 24KB. 16 K-iterations.
__device__ __forceinline__ void gemm64x128(const bf16_t* __restrict__ A,
                                           const bf16_t* __restrict__ W,
                                           int tileM, int tileN, char* smem,
                                           floatx4 acc[2][4]) {
  bf16_t* As = (bf16_t*)smem;              // [64][64], chunk-swizzled
  bf16_t* Bs = (bf16_t*)(smem + 8192);     // [128][64], chunk-swizzled
  const int tid = threadIdx.x;
  const int lane = tid & 63;
  const int quad = lane >> 4;
  const int l15 = lane & 15;
  const int wid = tid >> 6;
  const int waveM = (wid >> 1) * 32;
  const int waveN = (wid & 1) * 64;
  const int swz = l15 & 7;
  for (int i = 0; i < 2; ++i)
    for (int j = 0; j < 4; ++j)
      for (int r = 0; r < 4; ++r) acc[i][j][r] = 0.0f;

  const int r0 = tid >> 3;
  const int sc = ((tid & 7) ^ (r0 & 7)) << 3;
  const size_t abase = (size_t)(tileM + r0) * 1024 + sc;
  const size_t bbase = (size_t)(tileN + r0) * 1024 + sc;
  const int ldbase = (tid & ~63) * 16;

  for (int kt = 0; kt < 1024; kt += 64) {
    if (kt) __syncthreads();
    for (int j = 0; j < 2; ++j)
      async16(A + abase + (size_t)j * 32 * 1024 + kt, smem + j * 4096 + ldbase);
    for (int j = 0; j < 4; ++j)
      async16(W + bbase + (size_t)j * 32 * 1024 + kt, smem + 8192 + j * 4096 + ldbase);
    __syncthreads();
    for (int kk = 0; kk < 2; ++kk) {
      const int cq = (((kk << 2) + quad) ^ swz) << 3;
      bf16x8 af[2], bfr[4];
      for (int rb = 0; rb < 2; ++rb)
        af[rb] = *(const bf16x8*)&As[(waveM + rb * 16 + l15) * 64 + cq];
      for (int cb = 0; cb < 4; ++cb)
        bfr[cb] = *(const bf16x8*)&Bs[(waveN + cb * 16 + l15) * 64 + cq];
      for (int rb = 0; rb < 2; ++rb)
        for (int cb = 0; cb < 4; ++cb)
          acc[rb][cb] = __builtin_amdgcn_mfma_f32_16x16x32_bf16(af[rb], bfr[cb],
                                                                acc[rb][cb], 0, 0, 0);
    }
  }
}

// ---------------- QKV projection, 64x128 tiles (grid 8 x 64 x 3 = 1536 blocks) -------
// V is written with the PV key-permutation baked into the token index within each
// 64-token block: stored pos (32c+8q+4b+r) holds token (2c+b)*16+4q+r. This makes
// the attention PV A-operand a single aligned ds_read_b128.
__global__ __launch_bounds__(256) void proj_qkv(
    const bf16_t* __restrict__ xb, const bf16_t* __restrict__ wq,
    const bf16_t* __restrict__ wk, const bf16_t* __restrict__ wv,
    const float* __restrict__ cbias, const float* __restrict__ cv,
    bf16_t* __restrict__ qb, bf16_t* __restrict__ kb, bf16_t* __restrict__ vtb) {
  __shared__ __align__(16) char smem[24576];   // gemm staging 24KB; epilogue <= 18.4KB
  const int mode = blockIdx.z;
  const bf16_t* W = (mode == 0) ? wq : ((mode == 1) ? wk : wv);
  const int tileM = blockIdx.y * 64, tileN = blockIdx.x * 128;
  floatx4 acc[2][4];
  gemm64x128(xb, W, tileM, tileN, smem, acc);
  const int tid = threadIdx.x, lane = tid & 63, quad = lane >> 4, l15 = lane & 15,
            wid = tid >> 6;
  const int waveM = (wid >> 1) * 32, waveN = (wid & 1) * 64;
  bf16_t* T = (bf16_t*)smem;
  __syncthreads();                                      // gemm LDS reads done
  for (int rb = 0; rb < 2; ++rb)
    for (int cb = 0; cb < 4; ++cb)
      for (int r = 0; r < 4; ++r) {
        int rl = waveM + rb * 16 + quad * 4 + r;        // token (local, 0..63)
        int cl = waveN + cb * 16 + l15;                 // channel (local, 0..127)
        float v = acc[rb][cb][r];
        if (mode == 0)
          v += cbias[tileN + cl] * cv[(size_t)(tileM + rl) * 1024 + tileN + cl];
        if (mode == 2)                                  // PV-permuted token position
          T[cl * 72 + (waveM + quad * 8 + rb * 4 + r)] = (bf16_t)v;
        else
          T[rl * 136 + cl] = (bf16_t)v;                 // [token 64][channel 128+pad]
      }
  __syncthreads();
  if (mode == 2) {
    // V^T: 128 channels x 64 tokens; 2 threads/row, 32 tokens each
    const int rowi = tid >> 1, half = tid & 1;
    const bf16_t* src = T + rowi * 72 + half * 32;
    int n = tileN + rowi;                               // global channel = h*64+d
    int b = tileM >> 11;
    int t0 = (tileM & 2047) + half * 32;
    bf16_t* dst = vtb + ((size_t)b * 1024 + n) * 2048 + t0;
    for (int i = 0; i < 4; ++i) *(bf16x8*)(dst + i * 8) = *(const bf16x8*)(src + i * 8);
  } else {
    // Q/K: 64 tokens x 128 channels; 4 threads/row, 32 channels each
    const int rowi = tid >> 2, qtr = tid & 3;
    const bf16_t* src = T + rowi * 136 + qtr * 32;
    int tg = tileM + rowi;
    int b = tg >> 11, t = tg & 2047;
    int n0 = tileN + qtr * 32;
    int h = n0 >> 6;
    bf16_t* base = (mode == 0) ? qb : kb;
    bf16_t* dst = base + ((size_t)(b * 16 + h) * 2048 + t) * 64 + (n0 & 63);
    for (int i = 0; i < 4; ++i) *(bf16x8*)(dst + i * 8) = *(const bf16x8*)(src + i * 8);
  }
}

// ---------------- flash attention, causal, swapped-operand (S^T / O^T) ----------------
// S^T = K.Q^T: one query per lane (col=l15) -> softmax rows in-register (2 shfls).
// P^T stays in-lane (B-operand = in-lane repack); V is pre-permuted in HBM so the
// PV A-operand is a single aligned swizzled ds_read_b128. O^T = V^T.P^T.
__global__ __launch_bounds__(256) void attn_fwd(
    const bf16_t* __restrict__ qb, const bf16_t* __restrict__ kb,
    const bf16_t* __restrict__ vtb, bf16_t* __restrict__ ob) {
  __shared__ __align__(16) bf16_t Qs[64 * 64];      // [t][d], chunk-swizzled
  __shared__ __align__(16) bf16_t Ks[2][64 * 64];   // [key][d], swizzled
  __shared__ __align__(16) bf16_t Vs[2][64 * 64];   // [d][key-permuted], swizzled
  const int bh = blockIdx.x;
  const int qt = 31 - blockIdx.y;                   // heavy blocks dispatch first
  const int q0 = qt * 64;
  const int tid = threadIdx.x, lane = tid & 63, w = tid >> 6, quad = lane >> 4,
            l15 = lane & 15;

  const int sr = tid >> 3;                 // row 0..31 (and +32)
  const int sc = (tid & 7) ^ (sr & 7);     // swizzled source chunk
  const int ldst = (tid & ~63) * 16;       // wave-uniform byte offset in tile
  const int swz = l15 & 7;                 // read-side swizzle key

  {
    const bf16_t* gq = qb + ((size_t)bh * 2048 + q0 + sr) * 64 + sc * 8;
    async16(gq, (char*)Qs + ldst);
    async16(gq + 32 * 64, (char*)Qs + ldst + 4096);
  }

  floatx4 O[4];   // O^T: [db], reg r -> d = db*16+quad*4+r, q = w*16+l15
  for (int d = 0; d < 4; ++d)
    for (int r = 0; r < 4; ++r) O[d][r] = 0.f;
  float m_c = -1e30f, l_c = 0.f;
  const float SC = 0.125f * LOG2E;   // 1/sqrt(64) folded into exp2 domain
  const floatx4 zero4 = {0.f, 0.f, 0.f, 0.f};

  // prefetch tile 0 into buf 0
  {
    const bf16_t* gk = kb + ((size_t)bh * 2048 + sr) * 64 + sc * 8;
    async16(gk, (char*)Ks[0] + ldst);
    async16(gk + 32 * 64, (char*)Ks[0] + ldst + 4096);
    const bf16_t* gv = vtb + ((size_t)bh * 64 + sr) * 2048 + sc * 8;
    async16(gv, (char*)Vs[0] + ldst);
    async16(gv + (size_t)32 * 2048, (char*)Vs[0] + ldst + 4096);
  }
  __syncthreads();

  // loop-invariant Q fragments (B-operand: B[k=d][n=q], q = w*16+l15)
  bf16x8 qf[2];
  for (int ks = 0; ks < 2; ++ks) {
    const int cq = (ks * 4 + quad) ^ swz;
    qf[ks] = *(const bf16x8*)&Qs[(w * 16 + l15) * 64 + cq * 8];
  }

  for (int kt = 0; kt <= qt; ++kt) {
    const int cur = kt & 1;
    if (kt < qt) {           // prefetch kt+1 into other buffer (overlaps compute)
      const int nxt = cur ^ 1;
      const bf16_t* gk2 = kb + ((size_t)bh * 2048 + (kt + 1) * 64 + sr) * 64 + sc * 8;
      async16(gk2, (char*)Ks[nxt] + ldst);
      async16(gk2 + 32 * 64, (char*)Ks[nxt] + ldst + 4096);
      const bf16_t* gv2 = vtb + ((size_t)bh * 64 + sr) * 2048 + (size_t)(kt + 1) * 64 + sc * 8;
      async16(gv2, (char*)Vs[nxt] + ldst);
      async16(gv2 + (size_t)32 * 2048, (char*)Vs[nxt] + ldst + 4096);
    }
    // S^T = K x Q^T : s[kbt] covers keys kbt*16+quad*4+r, query w*16+l15
    floatx4 s[4];
    {
      const int cq0 = (quad ^ swz) << 3;          // ks=0 chunk
      const int cq1 = ((4 + quad) ^ swz) << 3;    // ks=1 chunk
      for (int kbt = 0; kbt < 4; ++kbt) {
        bf16x8 kf0 = *(const bf16x8*)&Ks[cur][(kbt * 16 + l15) * 64 + cq0];
        s[kbt] = __builtin_amdgcn_mfma_f32_16x16x32_bf16(kf0, qf[0], zero4, 0, 0, 0);
      }
      for (int kbt = 0; kbt < 4; ++kbt) {
        bf16x8 kf1 = *(const bf16x8*)&Ks[cur][(kbt * 16 + l15) * 64 + cq1];
        s[kbt] = __builtin_amdgcn_mfma_f32_16x16x32_bf16(kf1, qf[1], s[kbt], 0, 0, 0);
      }
    }
    // causal mask only on the diagonal tile (wave-uniform branch)
    if (kt == qt) {
      const int qloc = w * 16 + l15;
      for (int kbt = 0; kbt < 4; ++kbt)
        for (int r = 0; r < 4; ++r)
          if (kbt * 16 + quad * 4 + r > qloc) s[kbt][r] = -1e30f;
    }
    // row-max: 15 in-lane fmax + 2 cross-quad shfls
    float mx = s[0][0];
    for (int i = 0; i < 4; ++i)
      for (int r = 0; r < 4; ++r) mx = fmaxf(mx, s[i][r]);
    mx = fmaxf(mx, __shfl_xor(mx, 16));
    mx = fmaxf(mx, __shfl_xor(mx, 32));
    const float m_new = fmaxf(m_c, mx);
    const float alpha = exp2f((m_c - m_new) * SC);
    const float msc = m_new * SC;
    m_c = m_new;
    float p[4][4];
    float rs = 0.f;
    for (int i = 0; i < 4; ++i)
      for (int r = 0; r < 4; ++r) {
        float v = exp2f(fmaf(s[i][r], SC, -msc));
        p[i][r] = v;
        rs += v;
      }
    rs += __shfl_xor(rs, 16);
    rs += __shfl_xor(rs, 32);
    l_c = l_c * alpha + rs;
    for (int db = 0; db < 4; ++db)
      for (int r = 0; r < 4; ++r) O[db][r] *= alpha;
    // pack p into bf16 pairs: pk[i][rr] = keys i*16 + quad*4 + {2rr, 2rr+1}
    unsigned pk[4][2];
    for (int i = 0; i < 4; ++i)
      for (int rr = 0; rr < 2; ++rr) {
        bf16x2 t2;
        t2[0] = (bf16_t)p[i][2 * rr];
        t2[1] = (bf16_t)p[i][2 * rr + 1];
        pk[i][rr] = __builtin_bit_cast(unsigned, t2);
      }
    // PV: B-operand = in-lane repack; A-operand = single swizzled b128 from the
    // pre-permuted V tile (position 32c+8*quad+4b+r holds key (2c+b)*16+4*quad+r).
    for (int c = 0; c < 2; ++c) {
      uintx4 bw;
      bw[0] = pk[2 * c][0];
      bw[1] = pk[2 * c][1];
      bw[2] = pk[2 * c + 1][0];
      bw[3] = pk[2 * c + 1][1];
      bf16x8 pfrag = __builtin_bit_cast(bf16x8, bw);
      const int cqv = (((c << 2) + quad) ^ swz) << 3;
      for (int db = 0; db < 4; ++db) {
        bf16x8 vf = *(const bf16x8*)&Vs[cur][(db * 16 + l15) * 64 + cqv];
        O[db] = __builtin_amdgcn_mfma_f32_16x16x32_bf16(vf, pfrag, O[db], 0, 0, 0);
      }
    }
    __syncthreads();  // drains prefetch vmcnt; all waves done reading cur
  }
  const int b = bh >> 4, h = bh & 15;
  const float inv = 1.0f / l_c;
  const int t = q0 + w * 16 + l15;
  for (int db = 0; db < 4; ++db) {
    bf16x4 o4;
    for (int r = 0; r < 4; ++r) o4[r] = (bf16_t)(O[db][r] * inv);
    *(bf16x4*)&ob[((size_t)b * 2048 + t) * 1024 + h * 64 + db * 16 + quad * 4] = o4;
  }
}

// ---------------- output projection: out = ob @ wo^T + bo (fp32 out) ----------------
__global__ __launch_bounds__(256) void proj_o(
    const bf16_t* __restrict__ ain, const bf16_t* __restrict__ wo,
    const float* __restrict__ bo, float* __restrict__ out) {
  __shared__ __align__(16) char smem[24576];
  const int tileM = blockIdx.y * 64, tileN = blockIdx.x * 128;
  floatx4 acc[2][4];
  gemm64x128(ain, wo, tileM, tileN, smem, acc);
  const int tid = threadIdx.x, lane = tid & 63, quad = lane >> 4, l15 = lane & 15,
            wid = tid >> 6;
  const int waveM = (wid >> 1) * 32, waveN = (wid & 1) * 64;
  for (int rb = 0; rb < 2; ++rb)
    for (int cb = 0; cb < 4; ++cb)
      for (int r = 0; r < 4; ++r) {
        int row = tileM + waveM + rb * 16 + quad * 4 + r;
        int col = tileN + waveN + cb * 16 + l15;
        out[(size_t)row * 1024 + col] = acc[rb][cb][r] + bo[col];
      }
}

extern "C" void kernel_launch(void* const* d_in, const int* in_sizes, int n_in,
                              void* d_out, int out_size, void* d_ws, size_t ws_size,
                              hipStream_t stream) {
  const float* x     = (const float*)d_in[0];
  // d_in[1] = mask: tril causal by construction -> handled analytically
  const float* cv    = (const float*)d_in[2];
  const float* wq    = (const float*)d_in[3];
  const float* wk    = (const float*)d_in[4];
  const float* wv    = (const float*)d_in[5];
  const float* wo    = (const float*)d_in[6];
  const float* bo    = (const float*)d_in[7];
  const float* cbias = (const float*)d_in[8];
  float* out = (float*)d_out;

  char* ws = (char*)d_ws;
  const size_t MB = 1 << 20;
  bf16_t* xb  = (bf16_t*)(ws + 0 * MB);    // [4096,1024]
  bf16_t* wqb = (bf16_t*)(ws + 8 * MB);    // [1024,1024]
  bf16_t* wkb = (bf16_t*)(ws + 10 * MB);
  bf16_t* wvb = (bf16_t*)(ws + 12 * MB);
  bf16_t* wob = (bf16_t*)(ws + 14 * MB);
  bf16_t* qb  = (bf16_t*)(ws + 16 * MB);   // [32][2048][64]
  bf16_t* kb  = (bf16_t*)(ws + 24 * MB);   // [32][2048][64]
  bf16_t* vtb = (bf16_t*)(ws + 32 * MB);   // [32][64][2048] (transposed, PV-permuted)
  bf16_t* ob  = (bf16_t*)(ws + 40 * MB);   // [4096,1024]

  cast_all<<<8192, 256, 0, stream>>>(x, wq, wk, wv, wo, xb);
  proj_qkv<<<dim3(8, 64, 3), 256, 0, stream>>>(xb, wqb, wkb, wvb, cbias, cv, qb, kb, vtb);
  attn_fwd<<<dim3(32, 32), 256, 0, stream>>>(qb, kb, vtb, ob);
  proj_o<<<dim3(8, 64), 256, 0, stream>>>(ob, wob, bo, out);
}